// Round 1
// baseline (829.510 us; speedup 1.0000x reference)
//
#include <hip/hip_runtime.h>

#define DD 384
#define NB 64
#define NATOM 8192
#define RB 394              // row buckets: icy+5, icy in [-5,388]
#define CB 26               // col buckets: (icx+16)>>4, icx in [-5,388]
#define NBKT (RB * CB)      // 10244
#define OFFSTRIDE (NBKT + 4)

typedef short short8 __attribute__((ext_vector_type(8)));
typedef float f32x4 __attribute__((ext_vector_type(4)));

// float -> bf16 (RNE) as ushort
__device__ inline unsigned bf1(float a) {
    unsigned u = __float_as_uint(a);
    return (u + 0x7FFFu + ((u >> 16) & 1u)) >> 16;
}
__device__ inline unsigned bfpack(float a, float b) {
    return bf1(a) | (bf1(b) << 16);
}

// Pose one atom -> (X, Y) in physical coords (identical code in count/scatter
// => bit-identical results).
__device__ inline float2 pose_one(const float* __restrict__ crd,
                                  const float* __restrict__ rot,
                                  const float* __restrict__ rot_init,
                                  const float* __restrict__ trans, int idx) {
    int b = idx >> 13;
    const float* p = crd + (long)idx * 3;
    float x0 = p[0], y0 = p[1], z0 = p[2];
    float q0 = x0 * rot_init[0] + y0 * rot_init[3] + z0 * rot_init[6] + trans[0];
    float q1 = x0 * rot_init[1] + y0 * rot_init[4] + z0 * rot_init[7] + trans[1];
    float q2 = x0 * rot_init[2] + y0 * rot_init[5] + z0 * rot_init[8] + trans[2];
    const float* R = rot + b * 9;
    float2 o;
    o.x = q0 * R[0] + q1 * R[1] + q2 * R[2];
    o.y = q0 * R[3] + q1 * R[4] + q2 * R[5];
    return o;
}

// ---------------------------------------------------------------------------
// Bucketing: count -> per-image flat exclusive scan -> scatter.
// ---------------------------------------------------------------------------
__global__ void count_atoms(const float* __restrict__ crd,
                            const float* __restrict__ rot,
                            const float* __restrict__ rot_init,
                            const float* __restrict__ trans,
                            int* __restrict__ counts) {
    int idx = blockIdx.x * 256 + threadIdx.x;
    float2 v = pose_one(crd, rot, rot_init, trans, idx);
    int icx = (int)rintf(v.x + 192.0f);
    int icy = (int)rintf(v.y + 192.0f);
    if (icx < -5 || icx > 388 || icy < -5 || icy > 388) return;
    int bi = (icy + 5) * CB + ((icx + 16) >> 4);
    atomicAdd(&counts[(idx >> 13) * NBKT + bi], 1);
}

__global__ __launch_bounds__(256) void bucket_scan(int* __restrict__ counts,
                                                   int* __restrict__ offs) {
    int b = blockIdx.x, t = threadIdx.x;
    const int PER = (NBKT + 255) / 256;  // 41
    int* cnt = counts + b * NBKT;
    int* off = offs + b * OFFSTRIDE;
    int base = t * PER;
    int s = 0;
    for (int i = 0; i < PER; i++) {
        int k = base + i;
        if (k < NBKT) s += cnt[k];
    }
    __shared__ int part[256];
    part[t] = s;
    __syncthreads();
    for (int d = 1; d < 256; d <<= 1) {
        int v = (t >= d) ? part[t - d] : 0;
        __syncthreads();
        part[t] += v;
        __syncthreads();
    }
    int run = (t == 0) ? 0 : part[t - 1];
    for (int i = 0; i < PER; i++) {
        int k = base + i;
        if (k < NBKT) {
            off[k] = run;
            run += cnt[k];
            cnt[k] = 0;  // reuse as scatter cursor
        }
    }
    if (base <= NBKT - 1 && NBKT - 1 < base + PER) off[NBKT] = run;  // total
}

__global__ void scatter_atoms(const float* __restrict__ crd,
                              const float* __restrict__ rot,
                              const float* __restrict__ rot_init,
                              const float* __restrict__ trans,
                              int* __restrict__ cursors,
                              const int* __restrict__ offs,
                              float2* __restrict__ sorted) {
    int idx = blockIdx.x * 256 + threadIdx.x;
    float2 v = pose_one(crd, rot, rot_init, trans, idx);
    int icx = (int)rintf(v.x + 192.0f);
    int icy = (int)rintf(v.y + 192.0f);
    if (icx < -5 || icx > 388 || icy < -5 || icy > 388) return;
    int b = idx >> 13;
    int bi = (icy + 5) * CB + ((icx + 16) >> 4);
    int pos = offs[b * OFFSTRIDE + bi] + atomicAdd(&cursors[b * NBKT + bi], 1);
    sorted[(long)b * NATOM + pos] = v;
}

// ---------------------------------------------------------------------------
// Scatter splat into an LDS tile. Block owns 32 rows x 384 cols; the fp32
// accumulator tile lives in LDS with a +-10-col pad (out-of-image columns
// land in the pad and are never written out => no col masks needed).
// Atoms are row-bucket-sorted, so the block's atom set is one contiguous
// range of `sorted`. Each atom is processed exactly once per overlapping
// row-tile (avg 1.31x) with 22 exps + 121 fused mul+LDS-atomic-adds.
// Work-efficient vs. the old gather (~18 redundant lane-visits/atom) and
// immune to the Gaussian x-density lane imbalance.
// ---------------------------------------------------------------------------
#define TROWS 32
#define TW 405  // 10 pad + 384 + 10 pad (=404) + 1 for conflict-free writeout

__global__ __launch_bounds__(256) void splat_tile(const float2* __restrict__ sorted,
                                                  const int* __restrict__ offs,
                                                  float* __restrict__ img) {
    __shared__ float tile[TROWS][TW];
    int b = blockIdx.y;
    int r0 = blockIdx.x * TROWS;
    int tid = threadIdx.x;

    for (int i = tid; i < TROWS * TW; i += 256) ((float*)tile)[i] = 0.0f;
    __syncthreads();

    const int* off = offs + b * OFFSTRIDE;
    const float2* srt = sorted + (long)b * NATOM;
    // atoms with icy in [r0-5, r0+36] <=> rb in [r0, r0+41]; flat row-major
    // bucket scan makes that one contiguous range:
    int i0 = off[r0 * CB];
    int i1 = off[(r0 + 42) * CB];  // r0 max 352 -> index 10244 == NBKT (total)
    const float c = 1.0f / 4.5f;

    for (int i = i0 + tid; i < i1; i += 256) {
        float2 v = srt[i];
        float X = v.x, Yc = v.y;
        int icx = (int)rintf(X + 192.0f);
        int icy = (int)rintf(Yc + 192.0f);
        float gx[11];
#pragma unroll
        for (int dx = 0; dx < 11; dx++) {
            float d = (float)(icx - 5 + dx - 192) - X;
            gx[dx] = __expf(-d * d * c);
        }
        // lds col for dx: (icx-5+dx) + 10 pad = icx+5+dx, in [0, 403]
        float* base = &tile[0][0] + (icx + 5);
#pragma unroll
        for (int dy = 0; dy < 11; dy++) {
            int rr = icy - 5 + dy - r0;
            if ((unsigned)rr < (unsigned)TROWS) {
                float fy = (float)(icy - 5 + dy - 192) - Yc;
                float gy = __expf(-fy * fy * c);
                float* dst = base + rr * TW;
#pragma unroll
                for (int dx = 0; dx < 11; dx++)
                    atomicAdd(&dst[dx], gy * gx[dx]);
            }
        }
    }
    __syncthreads();

    float* dstg = img + ((long)b * DD + r0) * DD;
    for (int k = tid; k < TROWS * DD; k += 256) {
        int r = k / DD, col = k - r * DD;
        dstg[r * DD + col] = tile[r][col + 10];
    }
}

// ---------------------------------------------------------------------------
// DFT-derived weights (bf16): Bt1 = [U; S] (768x384), Bt2 = [U|-2S] (384x768).
// y = U*Y*U - 2*S*Y*S == Re(f)-Im(f) of double-fftshifted FFT2.
// ---------------------------------------------------------------------------
__global__ void gen_w(unsigned short* __restrict__ Bt1,
                      unsigned short* __restrict__ Bt2) {
    int idx = blockIdx.x * 256 + threadIdx.x;
    if (idx >= DD * DD) return;
    int i = idx / DD, j = idx % DD;
    int t = (i - 192) * (j - 192);
    int r = t % DD;
    if (r < 0) r += DD;
    float th = (float)r * (6.28318530717958647692f / (float)DD);
    float s = sinf(th), c = cosf(th);
    Bt1[i * DD + j] = (unsigned short)bf1(c + s);
    Bt1[(DD + i) * DD + j] = (unsigned short)bf1(s);
    Bt2[i * 768 + j] = (unsigned short)bf1(c + s);
    Bt2[i * 768 + 384 + j] = (unsigned short)bf1(-2.0f * s);
}

// ---------------------------------------------------------------------------
// bf16 MFMA GEMM (proven config): C[i][j] = sum_k A[i][k] * Bg[j][k]
// ---------------------------------------------------------------------------
template <bool AF32, bool CBF16>
__global__ __launch_bounds__(256) void gemm_mfma(const void* __restrict__ Ag, long sA,
                                                 const unsigned short* __restrict__ Bg,
                                                 void* __restrict__ Cg, long sC,
                                                 int K, int ldc) {
    __shared__ uint4 lds4[2048];  // A: [0,1024), B: [1024,2048)

    int bz = blockIdx.z;
    int m0 = blockIdx.y * 128, n0 = blockIdx.x * 128;
    int tid = threadIdx.x;
    int lane = tid & 63, w = tid >> 6;
    int wm = w >> 1, wn = w & 1;

    f32x4 acc[4][4];
#pragma unroll
    for (int i = 0; i < 4; i++)
#pragma unroll
        for (int j = 0; j < 4; j++) acc[i][j] = (f32x4){0.f, 0.f, 0.f, 0.f};

    const float* Af = (const float*)Ag + (long)bz * sA;
    const unsigned short* Ah = (const unsigned short*)Ag + (long)bz * sA;

    for (int k0 = 0; k0 < K; k0 += 64) {
        __syncthreads();
#pragma unroll
        for (int cc = 0; cc < 4; cc++) {
            int c = tid + cc * 256;
            int m = c >> 3, kc = (c & 7) << 3;
            int li = ((m >> 4) * 2 + (kc >> 5)) * 64 +
                     ((m & 15) | (((kc >> 3) & 3) << 4));
            uint4 wv;
            if (AF32) {
                const float* p = Af + (long)(m0 + m) * K + k0 + kc;
                float4 lo = *(const float4*)p;
                float4 hi = *(const float4*)(p + 4);
                wv.x = bfpack(lo.x, lo.y); wv.y = bfpack(lo.z, lo.w);
                wv.z = bfpack(hi.x, hi.y); wv.w = bfpack(hi.z, hi.w);
            } else {
                wv = *(const uint4*)(Ah + (long)(m0 + m) * K + k0 + kc);
            }
            lds4[li] = wv;
            lds4[1024 + li] = *(const uint4*)(Bg + (long)(n0 + m) * K + k0 + kc);
        }
        __syncthreads();
#pragma unroll
        for (int ki = 0; ki < 2; ki++) {
            short8 a[4], bfr[4];
#pragma unroll
            for (int i = 0; i < 4; i++)
                a[i] = *(const short8*)&lds4[((wm * 4 + i) * 2 + ki) * 64 + lane];
#pragma unroll
            for (int j = 0; j < 4; j++)
                bfr[j] = *(const short8*)&lds4[1024 + ((wn * 4 + j) * 2 + ki) * 64 + lane];
#pragma unroll
            for (int i = 0; i < 4; i++)
#pragma unroll
                for (int j = 0; j < 4; j++)
                    acc[i][j] = __builtin_amdgcn_mfma_f32_16x16x32_bf16(
                        a[i], bfr[j], acc[i][j], 0, 0, 0);
        }
    }

    int quad = lane >> 4, col0 = lane & 15;
#pragma unroll
    for (int i = 0; i < 4; i++)
#pragma unroll
        for (int j = 0; j < 4; j++)
#pragma unroll
            for (int r = 0; r < 4; r++) {
                int row = m0 + (wm * 4 + i) * 16 + quad * 4 + r;
                int cc2 = n0 + (wn * 4 + j) * 16 + col0;
                if (CBF16)
                    ((unsigned short*)Cg + (long)bz * sC)[(long)row * ldc + cc2] =
                        (unsigned short)bf1(acc[i][j][r]);
                else
                    ((float*)Cg + (long)bz * sC)[(long)row * ldc + cc2] = acc[i][j][r];
            }
}

// ---------------------------------------------------------------------------
// In-place fold-transpose of Z [64][384][768] bf16 (left/right 384x384 blocks
// transposed independently; one thread per r<c pair).
// ---------------------------------------------------------------------------
__global__ __launch_bounds__(256) void fold_transpose(unsigned short* __restrict__ Z) {
    long idx = (long)blockIdx.x * 256 + threadIdx.x;
    int b = (int)(idx / (DD * DD));
    int rc = (int)(idx % (DD * DD));
    int r = rc / DD, c = rc % DD;
    if (r >= c) return;
    unsigned short* Zb = Z + (long)b * DD * 768;
    unsigned short t0 = Zb[r * 768 + c];
    Zb[r * 768 + c] = Zb[c * 768 + r];
    Zb[c * 768 + r] = t0;
    unsigned short t1 = Zb[r * 768 + 384 + c];
    Zb[r * 768 + 384 + c] = Zb[c * 768 + 384 + r];
    Zb[c * 768 + 384 + r] = t1;
}

// ---------------------------------------------------------------------------
// In-place fp32 transpose of y [64][384][384] (stage 2 produces y^T).
// ---------------------------------------------------------------------------
__global__ __launch_bounds__(256) void transpose_inplace_f32(float* __restrict__ Yo) {
    long idx = (long)blockIdx.x * 256 + threadIdx.x;
    int b = (int)(idx / (DD * DD));
    int rc = (int)(idx % (DD * DD));
    int r = rc / DD, c = rc % DD;
    if (r >= c) return;
    float* Yb = Yo + (long)b * DD * DD;
    float t = Yb[r * DD + c];
    Yb[r * DD + c] = Yb[c * DD + r];
    Yb[c * DD + r] = t;
}

extern "C" void kernel_launch(void* const* d_in, const int* in_sizes, int n_in,
                              void* d_out, int out_size, void* d_ws, size_t ws_size,
                              hipStream_t stream) {
    const float* crd      = (const float*)d_in[0];
    const float* rot      = (const float*)d_in[1];
    const float* rot_init = (const float*)d_in[2];
    const float* trans    = (const float*)d_in[3];

    float* out   = (float*)d_out;
    float* y     = out;                          // [64,384,384] hartley (fp32)
    float* yreal = out + (size_t)NB * DD * DD;   // [64,384,384] real image

    char* ws = (char*)d_ws;
    unsigned short* Bt1 = (unsigned short*)ws;              // [U;S]   768x384
    unsigned short* Bt2 = (unsigned short*)(ws + 589824);   // [U|-2S] 384x768
    char* Zb = ws + 1179648;                                // Z region (37.7MB)
    unsigned short* Z = (unsigned short*)Zb;                // 64x384x768 bf16
    // Bucketing scratch aliases Z (all dead before stage-1 GEMM writes Z):
    int*    counts = (int*)Zb;                              // 2,622,464 B
    int*    offs   = (int*)(Zb + 2622464);                  // 2,623,488 B
    float2* sorted = (float2*)(Zb + 5245952);               // 4,194,304 B

    hipMemsetAsync(counts, 0, (size_t)NB * NBKT * 4, stream);

    count_atoms<<<(NB * NATOM) / 256, 256, 0, stream>>>(crd, rot, rot_init, trans, counts);
    bucket_scan<<<NB, 256, 0, stream>>>(counts, offs);
    scatter_atoms<<<(NB * NATOM) / 256, 256, 0, stream>>>(crd, rot, rot_init, trans,
                                                          counts, offs, sorted);
    splat_tile<<<dim3(12, NB), 256, 0, stream>>>(sorted, offs, yreal);

    gen_w<<<(DD * DD + 255) / 256, 256, 0, stream>>>(Bt1, Bt2);

    // Stage 1: Z = [Y*U | Y*S]  (A fp32 -> C bf16), M=384, N=768, K=384.
    gemm_mfma<true, true><<<dim3(6, 3, NB), 256, 0, stream>>>(
        (const void*)yreal, (long)DD * DD, Bt1, (void*)Z, (long)DD * 768, DD, 768);

    // Fold-transpose Z in place -> Zt[v][k] = (YU)[k][v] | (YS)[k-384][v]
    fold_transpose<<<(NB * DD * DD) / 256, 256, 0, stream>>>(Z);

    // Stage 2: C2 = y^T  (C2[i][j] = sum_k Zt[i][k]*Bt2[j][k]), M=N=384, K=768.
    gemm_mfma<false, false><<<dim3(3, 3, NB), 256, 0, stream>>>(
        (const void*)Z, (long)DD * 768, Bt2, (void*)y, (long)DD * DD, 768, DD);

    // y^T -> y in place
    transpose_inplace_f32<<<(NB * DD * DD) / 256, 256, 0, stream>>>(y);
}

// Round 2
// 828.194 us; speedup vs baseline: 1.0016x; 1.0016x over previous
//
#include <hip/hip_runtime.h>

#define DD 384
#define NB 64
#define NATOM 8192
#define RB 394              // row buckets: icy+5, icy in [-5,388]
#define CB 26               // col buckets: (icx+16)>>4, icx in [-5,388]
#define NBKT (RB * CB)      // 10244
#define OFFSTRIDE (NBKT + 4)

typedef short short8 __attribute__((ext_vector_type(8)));
typedef float f32x4 __attribute__((ext_vector_type(4)));

// float -> bf16 (RNE) as ushort
__device__ inline unsigned bf1(float a) {
    unsigned u = __float_as_uint(a);
    return (u + 0x7FFFu + ((u >> 16) & 1u)) >> 16;
}
__device__ inline unsigned bfpack(float a, float b) {
    return bf1(a) | (bf1(b) << 16);
}

// Pose one atom -> (X, Y) in physical coords (identical code in count/scatter
// => bit-identical results).
__device__ inline float2 pose_one(const float* __restrict__ crd,
                                  const float* __restrict__ rot,
                                  const float* __restrict__ rot_init,
                                  const float* __restrict__ trans, int idx) {
    int b = idx >> 13;
    const float* p = crd + (long)idx * 3;
    float x0 = p[0], y0 = p[1], z0 = p[2];
    float q0 = x0 * rot_init[0] + y0 * rot_init[3] + z0 * rot_init[6] + trans[0];
    float q1 = x0 * rot_init[1] + y0 * rot_init[4] + z0 * rot_init[7] + trans[1];
    float q2 = x0 * rot_init[2] + y0 * rot_init[5] + z0 * rot_init[8] + trans[2];
    const float* R = rot + b * 9;
    float2 o;
    o.x = q0 * R[0] + q1 * R[1] + q2 * R[2];
    o.y = q0 * R[3] + q1 * R[4] + q2 * R[5];
    return o;
}

// ---------------------------------------------------------------------------
// Bucketing: count -> per-image flat exclusive scan -> scatter.
// ---------------------------------------------------------------------------
__global__ void count_atoms(const float* __restrict__ crd,
                            const float* __restrict__ rot,
                            const float* __restrict__ rot_init,
                            const float* __restrict__ trans,
                            int* __restrict__ counts) {
    int idx = blockIdx.x * 256 + threadIdx.x;
    float2 v = pose_one(crd, rot, rot_init, trans, idx);
    int icx = (int)rintf(v.x + 192.0f);
    int icy = (int)rintf(v.y + 192.0f);
    if (icx < -5 || icx > 388 || icy < -5 || icy > 388) return;
    int bi = (icy + 5) * CB + ((icx + 16) >> 4);
    atomicAdd(&counts[(idx >> 13) * NBKT + bi], 1);
}

__global__ __launch_bounds__(256) void bucket_scan(int* __restrict__ counts,
                                                   int* __restrict__ offs) {
    int b = blockIdx.x, t = threadIdx.x;
    const int PER = (NBKT + 255) / 256;  // 41
    int* cnt = counts + b * NBKT;
    int* off = offs + b * OFFSTRIDE;
    int base = t * PER;
    int s = 0;
    for (int i = 0; i < PER; i++) {
        int k = base + i;
        if (k < NBKT) s += cnt[k];
    }
    __shared__ int part[256];
    part[t] = s;
    __syncthreads();
    for (int d = 1; d < 256; d <<= 1) {
        int v = (t >= d) ? part[t - d] : 0;
        __syncthreads();
        part[t] += v;
        __syncthreads();
    }
    int run = (t == 0) ? 0 : part[t - 1];
    for (int i = 0; i < PER; i++) {
        int k = base + i;
        if (k < NBKT) {
            off[k] = run;
            run += cnt[k];
            cnt[k] = 0;  // reuse as scatter cursor
        }
    }
    if (base <= NBKT - 1 && NBKT - 1 < base + PER) off[NBKT] = run;  // total
}

__global__ void scatter_atoms(const float* __restrict__ crd,
                              const float* __restrict__ rot,
                              const float* __restrict__ rot_init,
                              const float* __restrict__ trans,
                              int* __restrict__ cursors,
                              const int* __restrict__ offs,
                              float2* __restrict__ sorted) {
    int idx = blockIdx.x * 256 + threadIdx.x;
    float2 v = pose_one(crd, rot, rot_init, trans, idx);
    int icx = (int)rintf(v.x + 192.0f);
    int icy = (int)rintf(v.y + 192.0f);
    if (icx < -5 || icx > 388 || icy < -5 || icy > 388) return;
    int b = idx >> 13;
    int bi = (icy + 5) * CB + ((icx + 16) >> 4);
    int pos = offs[b * OFFSTRIDE + bi] + atomicAdd(&cursors[b * NBKT + bi], 1);
    sorted[(long)b * NATOM + pos] = v;
}

// ---------------------------------------------------------------------------
// Wave-cooperative scatter splat. Block owns 32 rows x 384 cols (fp32 tile in
// LDS, +-10-col pad so out-of-image columns land in the pad). One atom is
// processed per WAVE per iteration: lane l owns window elements l and l+64 of
// the 11x11 stencil (e -> dy=e/11, dx=e%11). The 64 lanes of every ds_add
// therefore hit 64 DISTINCT addresses -> no same-address atomic serialization
// (the failure mode of the per-thread-per-atom scatter: bucket-sorted order
// put all 64 lanes of a wave in the same 11x11 window, serializing every
// ds_add up to 64-deep). Bank conflicts: row stride 405 === 21 (mod 32);
// collisions need ddy*21+ddx===0 (mod 32) -> only (ddy=2,ddx=-10): rare 2-way
// (free). One exp per element: gy*gx = exp(-(dx^2+dy^2)*c).
// ---------------------------------------------------------------------------
#define TROWS 32
#define TW 405  // 10 pad + 384 + 10 pad (=404) + 1

__global__ __launch_bounds__(512) void splat_coop(const float2* __restrict__ sorted,
                                                  const int* __restrict__ offs,
                                                  float* __restrict__ img) {
    __shared__ float tile[TROWS][TW];
    int b = blockIdx.y;
    int r0 = blockIdx.x * TROWS;
    int tid = threadIdx.x;
    int lane = tid & 63, wv = tid >> 6;  // 8 waves

    for (int i = tid; i < TROWS * TW; i += 512) ((float*)tile)[i] = 0.0f;
    __syncthreads();

    const int* off = offs + b * OFFSTRIDE;
    const float2* srt = sorted + (long)b * NATOM;
    // atoms with icy in [r0-5, r0+36] <=> rb in [r0, r0+41]; flat row-major
    // bucket scan makes that one contiguous range:
    int i0 = off[r0 * CB];
    int i1 = off[(r0 + 42) * CB];  // r0 max 352 -> index 10244 == NBKT (total)

    // per-lane stencil elements (hoisted)
    int e0 = lane;                      // 0..63
    int dy0 = e0 / 11, dx0 = e0 - dy0 * 11;
    int e1 = lane + 64;                 // 64..127
    int dy1 = e1 / 11, dx1 = e1 - dy1 * 11;
    bool v1 = (e1 < 121);
    float fdx0 = (float)dx0, fdy0 = (float)dy0;
    float fdx1 = (float)dx1, fdy1 = (float)dy1;
    const float kneg = -(1.0f / 4.5f) * 1.44269504088896f;  // -c*log2(e)

    for (int i = i0 + wv; i < i1; i += 8) {
        float2 v = srt[i];               // wave-uniform broadcast load
        float X = v.x, Yc = v.y;
        int icx = (int)rintf(X + 192.0f);
        int icy = (int)rintf(Yc + 192.0f);
        float bx = (float)(icx - 197) - X;   // (icx-5-192) - X
        float by = (float)(icy - 197) - Yc;
        float fx0 = bx + fdx0, fy0 = by + fdy0;
        float fx1 = bx + fdx1, fy1 = by + fdy1;
        float g0 = exp2f((fx0 * fx0 + fy0 * fy0) * kneg);
        float g1 = exp2f((fx1 * fx1 + fy1 * fy1) * kneg);
        int colbase = icx + 5;               // lds col = colbase + dx, in [0,403]
        int rr0 = icy - 5 + dy0 - r0;
        int rr1 = icy - 5 + dy1 - r0;
        if ((unsigned)rr0 < (unsigned)TROWS) atomicAdd(&tile[rr0][colbase + dx0], g0);
        if (v1 && (unsigned)rr1 < (unsigned)TROWS) atomicAdd(&tile[rr1][colbase + dx1], g1);
    }
    __syncthreads();

    float* dstg = img + ((long)b * DD + r0) * DD;
    for (int k = tid; k < TROWS * DD; k += 512) {
        int r = k / DD, col = k - r * DD;
        dstg[r * DD + col] = tile[r][col + 10];
    }
}

// ---------------------------------------------------------------------------
// DFT-derived weights (bf16): Bt1 = [U; S] (768x384), Bt2 = [U|-2S] (384x768).
// y = U*Y*U - 2*S*Y*S == Re(f)-Im(f) of double-fftshifted FFT2.
// ---------------------------------------------------------------------------
__global__ void gen_w(unsigned short* __restrict__ Bt1,
                      unsigned short* __restrict__ Bt2) {
    int idx = blockIdx.x * 256 + threadIdx.x;
    if (idx >= DD * DD) return;
    int i = idx / DD, j = idx % DD;
    int t = (i - 192) * (j - 192);
    int r = t % DD;
    if (r < 0) r += DD;
    float th = (float)r * (6.28318530717958647692f / (float)DD);
    float s = sinf(th), c = cosf(th);
    Bt1[i * DD + j] = (unsigned short)bf1(c + s);
    Bt1[(DD + i) * DD + j] = (unsigned short)bf1(s);
    Bt2[i * 768 + j] = (unsigned short)bf1(c + s);
    Bt2[i * 768 + 384 + j] = (unsigned short)bf1(-2.0f * s);
}

// ---------------------------------------------------------------------------
// bf16 MFMA GEMM (proven config): C[i][j] = sum_k A[i][k] * Bg[j][k]
// ---------------------------------------------------------------------------
template <bool AF32, bool CBF16>
__global__ __launch_bounds__(256) void gemm_mfma(const void* __restrict__ Ag, long sA,
                                                 const unsigned short* __restrict__ Bg,
                                                 void* __restrict__ Cg, long sC,
                                                 int K, int ldc) {
    __shared__ uint4 lds4[2048];  // A: [0,1024), B: [1024,2048)

    int bz = blockIdx.z;
    int m0 = blockIdx.y * 128, n0 = blockIdx.x * 128;
    int tid = threadIdx.x;
    int lane = tid & 63, w = tid >> 6;
    int wm = w >> 1, wn = w & 1;

    f32x4 acc[4][4];
#pragma unroll
    for (int i = 0; i < 4; i++)
#pragma unroll
        for (int j = 0; j < 4; j++) acc[i][j] = (f32x4){0.f, 0.f, 0.f, 0.f};

    const float* Af = (const float*)Ag + (long)bz * sA;
    const unsigned short* Ah = (const unsigned short*)Ag + (long)bz * sA;

    for (int k0 = 0; k0 < K; k0 += 64) {
        __syncthreads();
#pragma unroll
        for (int cc = 0; cc < 4; cc++) {
            int c = tid + cc * 256;
            int m = c >> 3, kc = (c & 7) << 3;
            int li = ((m >> 4) * 2 + (kc >> 5)) * 64 +
                     ((m & 15) | (((kc >> 3) & 3) << 4));
            uint4 wv;
            if (AF32) {
                const float* p = Af + (long)(m0 + m) * K + k0 + kc;
                float4 lo = *(const float4*)p;
                float4 hi = *(const float4*)(p + 4);
                wv.x = bfpack(lo.x, lo.y); wv.y = bfpack(lo.z, lo.w);
                wv.z = bfpack(hi.x, hi.y); wv.w = bfpack(hi.z, hi.w);
            } else {
                wv = *(const uint4*)(Ah + (long)(m0 + m) * K + k0 + kc);
            }
            lds4[li] = wv;
            lds4[1024 + li] = *(const uint4*)(Bg + (long)(n0 + m) * K + k0 + kc);
        }
        __syncthreads();
#pragma unroll
        for (int ki = 0; ki < 2; ki++) {
            short8 a[4], bfr[4];
#pragma unroll
            for (int i = 0; i < 4; i++)
                a[i] = *(const short8*)&lds4[((wm * 4 + i) * 2 + ki) * 64 + lane];
#pragma unroll
            for (int j = 0; j < 4; j++)
                bfr[j] = *(const short8*)&lds4[1024 + ((wn * 4 + j) * 2 + ki) * 64 + lane];
#pragma unroll
            for (int i = 0; i < 4; i++)
#pragma unroll
                for (int j = 0; j < 4; j++)
                    acc[i][j] = __builtin_amdgcn_mfma_f32_16x16x32_bf16(
                        a[i], bfr[j], acc[i][j], 0, 0, 0);
        }
    }

    int quad = lane >> 4, col0 = lane & 15;
#pragma unroll
    for (int i = 0; i < 4; i++)
#pragma unroll
        for (int j = 0; j < 4; j++)
#pragma unroll
            for (int r = 0; r < 4; r++) {
                int row = m0 + (wm * 4 + i) * 16 + quad * 4 + r;
                int cc2 = n0 + (wn * 4 + j) * 16 + col0;
                if (CBF16)
                    ((unsigned short*)Cg + (long)bz * sC)[(long)row * ldc + cc2] =
                        (unsigned short)bf1(acc[i][j][r]);
                else
                    ((float*)Cg + (long)bz * sC)[(long)row * ldc + cc2] = acc[i][j][r];
            }
}

// ---------------------------------------------------------------------------
// In-place fold-transpose of Z [64][384][768] bf16 (left/right 384x384 blocks
// transposed independently; one thread per r<c pair).
// ---------------------------------------------------------------------------
__global__ __launch_bounds__(256) void fold_transpose(unsigned short* __restrict__ Z) {
    long idx = (long)blockIdx.x * 256 + threadIdx.x;
    int b = (int)(idx / (DD * DD));
    int rc = (int)(idx % (DD * DD));
    int r = rc / DD, c = rc % DD;
    if (r >= c) return;
    unsigned short* Zb = Z + (long)b * DD * 768;
    unsigned short t0 = Zb[r * 768 + c];
    Zb[r * 768 + c] = Zb[c * 768 + r];
    Zb[c * 768 + r] = t0;
    unsigned short t1 = Zb[r * 768 + 384 + c];
    Zb[r * 768 + 384 + c] = Zb[c * 768 + 384 + r];
    Zb[c * 768 + 384 + r] = t1;
}

// ---------------------------------------------------------------------------
// In-place fp32 transpose of y [64][384][384] (stage 2 produces y^T).
// ---------------------------------------------------------------------------
__global__ __launch_bounds__(256) void transpose_inplace_f32(float* __restrict__ Yo) {
    long idx = (long)blockIdx.x * 256 + threadIdx.x;
    int b = (int)(idx / (DD * DD));
    int rc = (int)(idx % (DD * DD));
    int r = rc / DD, c = rc % DD;
    if (r >= c) return;
    float* Yb = Yo + (long)b * DD * DD;
    float t = Yb[r * DD + c];
    Yb[r * DD + c] = Yb[c * DD + r];
    Yb[c * DD + r] = t;
}

extern "C" void kernel_launch(void* const* d_in, const int* in_sizes, int n_in,
                              void* d_out, int out_size, void* d_ws, size_t ws_size,
                              hipStream_t stream) {
    const float* crd      = (const float*)d_in[0];
    const float* rot      = (const float*)d_in[1];
    const float* rot_init = (const float*)d_in[2];
    const float* trans    = (const float*)d_in[3];

    float* out   = (float*)d_out;
    float* y     = out;                          // [64,384,384] hartley (fp32)
    float* yreal = out + (size_t)NB * DD * DD;   // [64,384,384] real image

    char* ws = (char*)d_ws;
    unsigned short* Bt1 = (unsigned short*)ws;              // [U;S]   768x384
    unsigned short* Bt2 = (unsigned short*)(ws + 589824);   // [U|-2S] 384x768
    char* Zb = ws + 1179648;                                // Z region (37.7MB)
    unsigned short* Z = (unsigned short*)Zb;                // 64x384x768 bf16
    // Bucketing scratch aliases Z (all dead before stage-1 GEMM writes Z):
    int*    counts = (int*)Zb;                              // 2,622,464 B
    int*    offs   = (int*)(Zb + 2622464);                  // 2,623,488 B
    float2* sorted = (float2*)(Zb + 5245952);               // 4,194,304 B

    hipMemsetAsync(counts, 0, (size_t)NB * NBKT * 4, stream);

    count_atoms<<<(NB * NATOM) / 256, 256, 0, stream>>>(crd, rot, rot_init, trans, counts);
    bucket_scan<<<NB, 256, 0, stream>>>(counts, offs);
    scatter_atoms<<<(NB * NATOM) / 256, 256, 0, stream>>>(crd, rot, rot_init, trans,
                                                          counts, offs, sorted);
    splat_coop<<<dim3(12, NB), 512, 0, stream>>>(sorted, offs, yreal);

    gen_w<<<(DD * DD + 255) / 256, 256, 0, stream>>>(Bt1, Bt2);

    // Stage 1: Z = [Y*U | Y*S]  (A fp32 -> C bf16), M=384, N=768, K=384.
    gemm_mfma<true, true><<<dim3(6, 3, NB), 256, 0, stream>>>(
        (const void*)yreal, (long)DD * DD, Bt1, (void*)Z, (long)DD * 768, DD, 768);

    // Fold-transpose Z in place -> Zt[v][k] = (YU)[k][v] | (YS)[k-384][v]
    fold_transpose<<<(NB * DD * DD) / 256, 256, 0, stream>>>(Z);

    // Stage 2: C2 = y^T  (C2[i][j] = sum_k Zt[i][k]*Bt2[j][k]), M=N=384, K=768.
    gemm_mfma<false, false><<<dim3(3, 3, NB), 256, 0, stream>>>(
        (const void*)Z, (long)DD * 768, Bt2, (void*)y, (long)DD * DD, 768, DD);

    // y^T -> y in place
    transpose_inplace_f32<<<(NB * DD * DD) / 256, 256, 0, stream>>>(y);
}

// Round 3
// 700.950 us; speedup vs baseline: 1.1834x; 1.1815x over previous
//
#include <hip/hip_runtime.h>

#define DD 384
#define NB 64
#define NATOM 8192
#define RB 394              // row buckets: icy+5, icy in [-5,388]
#define CB 26               // col buckets: (icx+16)>>4, icx in [-5,388]
#define NBKT (RB * CB)      // 10244
#define OFFSTRIDE (NBKT + 4)

typedef short short8 __attribute__((ext_vector_type(8)));
typedef float f32x4 __attribute__((ext_vector_type(4)));

// float -> bf16 (RNE) as ushort
__device__ inline unsigned bf1(float a) {
    unsigned u = __float_as_uint(a);
    return (u + 0x7FFFu + ((u >> 16) & 1u)) >> 16;
}
__device__ inline unsigned bfpack(float a, float b) {
    return bf1(a) | (bf1(b) << 16);
}

// Pose one atom -> (X, Y) in physical coords (identical code in count/scatter
// => bit-identical results).
__device__ inline float2 pose_one(const float* __restrict__ crd,
                                  const float* __restrict__ rot,
                                  const float* __restrict__ rot_init,
                                  const float* __restrict__ trans, int idx) {
    int b = idx >> 13;
    const float* p = crd + (long)idx * 3;
    float x0 = p[0], y0 = p[1], z0 = p[2];
    float q0 = x0 * rot_init[0] + y0 * rot_init[3] + z0 * rot_init[6] + trans[0];
    float q1 = x0 * rot_init[1] + y0 * rot_init[4] + z0 * rot_init[7] + trans[1];
    float q2 = x0 * rot_init[2] + y0 * rot_init[5] + z0 * rot_init[8] + trans[2];
    const float* R = rot + b * 9;
    float2 o;
    o.x = q0 * R[0] + q1 * R[1] + q2 * R[2];
    o.y = q0 * R[3] + q1 * R[4] + q2 * R[5];
    return o;
}

// ---------------------------------------------------------------------------
// Bucketing: count -> per-image flat exclusive scan -> scatter.
// ---------------------------------------------------------------------------
__global__ void count_atoms(const float* __restrict__ crd,
                            const float* __restrict__ rot,
                            const float* __restrict__ rot_init,
                            const float* __restrict__ trans,
                            int* __restrict__ counts) {
    int idx = blockIdx.x * 256 + threadIdx.x;
    float2 v = pose_one(crd, rot, rot_init, trans, idx);
    int icx = (int)rintf(v.x + 192.0f);
    int icy = (int)rintf(v.y + 192.0f);
    if (icx < -5 || icx > 388 || icy < -5 || icy > 388) return;
    int bi = (icy + 5) * CB + ((icx + 16) >> 4);
    atomicAdd(&counts[(idx >> 13) * NBKT + bi], 1);
}

__global__ __launch_bounds__(256) void bucket_scan(int* __restrict__ counts,
                                                   int* __restrict__ offs) {
    int b = blockIdx.x, t = threadIdx.x;
    const int PER = (NBKT + 255) / 256;  // 41
    int* cnt = counts + b * NBKT;
    int* off = offs + b * OFFSTRIDE;
    int base = t * PER;
    int s = 0;
    for (int i = 0; i < PER; i++) {
        int k = base + i;
        if (k < NBKT) s += cnt[k];
    }
    __shared__ int part[256];
    part[t] = s;
    __syncthreads();
    for (int d = 1; d < 256; d <<= 1) {
        int v = (t >= d) ? part[t - d] : 0;
        __syncthreads();
        part[t] += v;
        __syncthreads();
    }
    int run = (t == 0) ? 0 : part[t - 1];
    for (int i = 0; i < PER; i++) {
        int k = base + i;
        if (k < NBKT) {
            off[k] = run;
            run += cnt[k];
            cnt[k] = 0;  // reuse as scatter cursor
        }
    }
    if (base <= NBKT - 1 && NBKT - 1 < base + PER) off[NBKT] = run;  // total
}

__global__ void scatter_atoms(const float* __restrict__ crd,
                              const float* __restrict__ rot,
                              const float* __restrict__ rot_init,
                              const float* __restrict__ trans,
                              int* __restrict__ cursors,
                              const int* __restrict__ offs,
                              float2* __restrict__ sorted) {
    int idx = blockIdx.x * 256 + threadIdx.x;
    float2 v = pose_one(crd, rot, rot_init, trans, idx);
    int icx = (int)rintf(v.x + 192.0f);
    int icy = (int)rintf(v.y + 192.0f);
    if (icx < -5 || icx > 388 || icy < -5 || icy > 388) return;
    int b = idx >> 13;
    int bi = (icy + 5) * CB + ((icx + 16) >> 4);
    int pos = offs[b * OFFSTRIDE + bi] + atomicAdd(&cursors[b * NBKT + bi], 1);
    sorted[(long)b * NATOM + pos] = v;
}

// ---------------------------------------------------------------------------
// Atomic-free register-gather splat. LDS atomics are off the table: R1/R2
// measured ds_add_f32 at ~155 cyc/wave-op (~2.4 cyc/lane, serial regardless
// of address pattern) -> any scatter formulation floors at ~340us.
//
// Here one WAVE owns a 16x16 px tile; lanes form an 8x8 grid and each lane
// accumulates its 2x2 pixels (stride 8) in VGPRs. The wave walks the 26
// per-px-row bucket segments covering rows [r0-5, r0+20]; per row the col
// range is 3 contiguous 16-px buckets in the flat row-major scan (48px
// loaded, 26 in-range; out-of-x-range atoms are skipped by a wave-uniform
// branch). Per in-range atom: 4 exp2 + ~40 VALU for 4 outputs. Replication
// is only the tile-boundary overlap (avg 2.64x), all 64 lanes do useful
// work, and no atom is ever touched by more than one exp path per pixel.
// No LDS, no atomics, no zero-init, no separate writeback pass.
// ---------------------------------------------------------------------------
__global__ __launch_bounds__(256) void splat_gather(const float2* __restrict__ sorted,
                                                    const int* __restrict__ offs,
                                                    float* __restrict__ img) {
    int b = blockIdx.z;
    int wv = __builtin_amdgcn_readfirstlane((int)(threadIdx.x >> 6));
    int lane = threadIdx.x & 63;
    int tx = blockIdx.x * 4 + wv;      // 0..23
    int ty = blockIdx.y;               // 0..23
    int c0 = tx * 16, r0 = ty * 16;
    int lx = lane & 7, ly = lane >> 3; // 8x8 lane grid
    // lane owns cols {c0+lx, c0+lx+8}, rows {r0+ly, r0+ly+8}

    const int* off = offs + b * OFFSTRIDE;
    const float2* srt = sorted + (long)b * NATOM;

    int cb_lo = (c0 + 11) >> 4;          // icx >= c0-5
    int cb_end = ((c0 + 36) >> 4) + 1;   // icx <= c0+20 (end-exclusive bucket)

    float acc00 = 0.f, acc01 = 0.f, acc10 = 0.f, acc11 = 0.f;
    float pxf0 = (float)(c0 + lx - 192);
    float pyf0 = (float)(r0 + ly - 192);
    int px0 = c0 + lx, py0 = r0 + ly;
    const float kneg = -(1.0f / 4.5f) * 1.44269504088896f;  // -inv2s2*log2(e)

    for (int rb = r0; rb < r0 + 26; rb++) {  // icy = rb-5 in [r0-5, r0+20]
        int i0 = off[rb * CB + cb_lo];
        int i1 = off[rb * CB + cb_end];      // flat scan: next bucket's start
        for (int i = i0; i < i1; i++) {
            float2 v = srt[i];               // wave-uniform (scalar) load
            float X = v.x, Y = v.y;
            int icx = (int)rintf(X + 192.0f);
            if ((unsigned)(icx - c0 + 5) > 25u) continue;  // uniform x-skip
            int icy = (int)rintf(Y + 192.0f);
            float fx0 = pxf0 - X, fx1 = fx0 + 8.0f;
            float fy0 = pyf0 - Y, fy1 = fy0 + 8.0f;
            int dx = px0 - icx, dy = py0 - icy;
            float ex0 = ((unsigned)(dx + 5) < 11u) ? exp2f(fx0 * fx0 * kneg) : 0.0f;
            float ex1 = ((unsigned)(dx + 13) < 11u) ? exp2f(fx1 * fx1 * kneg) : 0.0f;
            float ey0 = ((unsigned)(dy + 5) < 11u) ? exp2f(fy0 * fy0 * kneg) : 0.0f;
            float ey1 = ((unsigned)(dy + 13) < 11u) ? exp2f(fy1 * fy1 * kneg) : 0.0f;
            acc00 += ex0 * ey0;
            acc01 += ex1 * ey0;
            acc10 += ex0 * ey1;
            acc11 += ex1 * ey1;
        }
    }

    float* dst = img + ((long)b * DD + r0 + ly) * DD + c0 + lx;
    dst[0] = acc00;
    dst[8] = acc01;
    dst[8 * DD] = acc10;
    dst[8 * DD + 8] = acc11;
}

// ---------------------------------------------------------------------------
// DFT-derived weights (bf16): Bt1 = [U; S] (768x384), Bt2 = [U|-2S] (384x768).
// y = U*Y*U - 2*S*Y*S == Re(f)-Im(f) of double-fftshifted FFT2.
// ---------------------------------------------------------------------------
__global__ void gen_w(unsigned short* __restrict__ Bt1,
                      unsigned short* __restrict__ Bt2) {
    int idx = blockIdx.x * 256 + threadIdx.x;
    if (idx >= DD * DD) return;
    int i = idx / DD, j = idx % DD;
    int t = (i - 192) * (j - 192);
    int r = t % DD;
    if (r < 0) r += DD;
    float th = (float)r * (6.28318530717958647692f / (float)DD);
    float s = sinf(th), c = cosf(th);
    Bt1[i * DD + j] = (unsigned short)bf1(c + s);
    Bt1[(DD + i) * DD + j] = (unsigned short)bf1(s);
    Bt2[i * 768 + j] = (unsigned short)bf1(c + s);
    Bt2[i * 768 + 384 + j] = (unsigned short)bf1(-2.0f * s);
}

// ---------------------------------------------------------------------------
// bf16 MFMA GEMM (proven config): C[i][j] = sum_k A[i][k] * Bg[j][k]
// ---------------------------------------------------------------------------
template <bool AF32, bool CBF16>
__global__ __launch_bounds__(256) void gemm_mfma(const void* __restrict__ Ag, long sA,
                                                 const unsigned short* __restrict__ Bg,
                                                 void* __restrict__ Cg, long sC,
                                                 int K, int ldc) {
    __shared__ uint4 lds4[2048];  // A: [0,1024), B: [1024,2048)

    int bz = blockIdx.z;
    int m0 = blockIdx.y * 128, n0 = blockIdx.x * 128;
    int tid = threadIdx.x;
    int lane = tid & 63, w = tid >> 6;
    int wm = w >> 1, wn = w & 1;

    f32x4 acc[4][4];
#pragma unroll
    for (int i = 0; i < 4; i++)
#pragma unroll
        for (int j = 0; j < 4; j++) acc[i][j] = (f32x4){0.f, 0.f, 0.f, 0.f};

    const float* Af = (const float*)Ag + (long)bz * sA;
    const unsigned short* Ah = (const unsigned short*)Ag + (long)bz * sA;

    for (int k0 = 0; k0 < K; k0 += 64) {
        __syncthreads();
#pragma unroll
        for (int cc = 0; cc < 4; cc++) {
            int c = tid + cc * 256;
            int m = c >> 3, kc = (c & 7) << 3;
            int li = ((m >> 4) * 2 + (kc >> 5)) * 64 +
                     ((m & 15) | (((kc >> 3) & 3) << 4));
            uint4 wv;
            if (AF32) {
                const float* p = Af + (long)(m0 + m) * K + k0 + kc;
                float4 lo = *(const float4*)p;
                float4 hi = *(const float4*)(p + 4);
                wv.x = bfpack(lo.x, lo.y); wv.y = bfpack(lo.z, lo.w);
                wv.z = bfpack(hi.x, hi.y); wv.w = bfpack(hi.z, hi.w);
            } else {
                wv = *(const uint4*)(Ah + (long)(m0 + m) * K + k0 + kc);
            }
            lds4[li] = wv;
            lds4[1024 + li] = *(const uint4*)(Bg + (long)(n0 + m) * K + k0 + kc);
        }
        __syncthreads();
#pragma unroll
        for (int ki = 0; ki < 2; ki++) {
            short8 a[4], bfr[4];
#pragma unroll
            for (int i = 0; i < 4; i++)
                a[i] = *(const short8*)&lds4[((wm * 4 + i) * 2 + ki) * 64 + lane];
#pragma unroll
            for (int j = 0; j < 4; j++)
                bfr[j] = *(const short8*)&lds4[1024 + ((wn * 4 + j) * 2 + ki) * 64 + lane];
#pragma unroll
            for (int i = 0; i < 4; i++)
#pragma unroll
                for (int j = 0; j < 4; j++)
                    acc[i][j] = __builtin_amdgcn_mfma_f32_16x16x32_bf16(
                        a[i], bfr[j], acc[i][j], 0, 0, 0);
        }
    }

    int quad = lane >> 4, col0 = lane & 15;
#pragma unroll
    for (int i = 0; i < 4; i++)
#pragma unroll
        for (int j = 0; j < 4; j++)
#pragma unroll
            for (int r = 0; r < 4; r++) {
                int row = m0 + (wm * 4 + i) * 16 + quad * 4 + r;
                int cc2 = n0 + (wn * 4 + j) * 16 + col0;
                if (CBF16)
                    ((unsigned short*)Cg + (long)bz * sC)[(long)row * ldc + cc2] =
                        (unsigned short)bf1(acc[i][j][r]);
                else
                    ((float*)Cg + (long)bz * sC)[(long)row * ldc + cc2] = acc[i][j][r];
            }
}

// ---------------------------------------------------------------------------
// In-place fold-transpose of Z [64][384][768] bf16 (left/right 384x384 blocks
// transposed independently; one thread per r<c pair).
// ---------------------------------------------------------------------------
__global__ __launch_bounds__(256) void fold_transpose(unsigned short* __restrict__ Z) {
    long idx = (long)blockIdx.x * 256 + threadIdx.x;
    int b = (int)(idx / (DD * DD));
    int rc = (int)(idx % (DD * DD));
    int r = rc / DD, c = rc % DD;
    if (r >= c) return;
    unsigned short* Zb = Z + (long)b * DD * 768;
    unsigned short t0 = Zb[r * 768 + c];
    Zb[r * 768 + c] = Zb[c * 768 + r];
    Zb[c * 768 + r] = t0;
    unsigned short t1 = Zb[r * 768 + 384 + c];
    Zb[r * 768 + 384 + c] = Zb[c * 768 + 384 + r];
    Zb[c * 768 + 384 + r] = t1;
}

// ---------------------------------------------------------------------------
// In-place fp32 transpose of y [64][384][384] (stage 2 produces y^T).
// ---------------------------------------------------------------------------
__global__ __launch_bounds__(256) void transpose_inplace_f32(float* __restrict__ Yo) {
    long idx = (long)blockIdx.x * 256 + threadIdx.x;
    int b = (int)(idx / (DD * DD));
    int rc = (int)(idx % (DD * DD));
    int r = rc / DD, c = rc % DD;
    if (r >= c) return;
    float* Yb = Yo + (long)b * DD * DD;
    float t = Yb[r * DD + c];
    Yb[r * DD + c] = Yb[c * DD + r];
    Yb[c * DD + r] = t;
}

extern "C" void kernel_launch(void* const* d_in, const int* in_sizes, int n_in,
                              void* d_out, int out_size, void* d_ws, size_t ws_size,
                              hipStream_t stream) {
    const float* crd      = (const float*)d_in[0];
    const float* rot      = (const float*)d_in[1];
    const float* rot_init = (const float*)d_in[2];
    const float* trans    = (const float*)d_in[3];

    float* out   = (float*)d_out;
    float* y     = out;                          // [64,384,384] hartley (fp32)
    float* yreal = out + (size_t)NB * DD * DD;   // [64,384,384] real image

    char* ws = (char*)d_ws;
    unsigned short* Bt1 = (unsigned short*)ws;              // [U;S]   768x384
    unsigned short* Bt2 = (unsigned short*)(ws + 589824);   // [U|-2S] 384x768
    char* Zb = ws + 1179648;                                // Z region (37.7MB)
    unsigned short* Z = (unsigned short*)Zb;                // 64x384x768 bf16
    // Bucketing scratch aliases Z (all dead before stage-1 GEMM writes Z):
    int*    counts = (int*)Zb;                              // 2,622,464 B
    int*    offs   = (int*)(Zb + 2622464);                  // 2,623,488 B
    float2* sorted = (float2*)(Zb + 5245952);               // 4,194,304 B

    hipMemsetAsync(counts, 0, (size_t)NB * NBKT * 4, stream);

    count_atoms<<<(NB * NATOM) / 256, 256, 0, stream>>>(crd, rot, rot_init, trans, counts);
    bucket_scan<<<NB, 256, 0, stream>>>(counts, offs);
    scatter_atoms<<<(NB * NATOM) / 256, 256, 0, stream>>>(crd, rot, rot_init, trans,
                                                          counts, offs, sorted);
    splat_gather<<<dim3(6, 24, NB), 256, 0, stream>>>(sorted, offs, yreal);

    gen_w<<<(DD * DD + 255) / 256, 256, 0, stream>>>(Bt1, Bt2);

    // Stage 1: Z = [Y*U | Y*S]  (A fp32 -> C bf16), M=384, N=768, K=384.
    gemm_mfma<true, true><<<dim3(6, 3, NB), 256, 0, stream>>>(
        (const void*)yreal, (long)DD * DD, Bt1, (void*)Z, (long)DD * 768, DD, 768);

    // Fold-transpose Z in place -> Zt[v][k] = (YU)[k][v] | (YS)[k-384][v]
    fold_transpose<<<(NB * DD * DD) / 256, 256, 0, stream>>>(Z);

    // Stage 2: C2 = y^T  (C2[i][j] = sum_k Zt[i][k]*Bt2[j][k]), M=N=384, K=768.
    gemm_mfma<false, false><<<dim3(3, 3, NB), 256, 0, stream>>>(
        (const void*)Z, (long)DD * 768, Bt2, (void*)y, (long)DD * DD, 768, DD);

    // y^T -> y in place
    transpose_inplace_f32<<<(NB * DD * DD) / 256, 256, 0, stream>>>(y);
}

// Round 4
// 492.704 us; speedup vs baseline: 1.6836x; 1.4227x over previous
//
#include <hip/hip_runtime.h>

#define DD 384
#define NB 64
#define NATOM 8192
#define RB 394              // row buckets: icy+5, icy in [-5,388]
#define CB 51               // col buckets: (icx+16)>>3, icx in [-5,388] -> [1,50]
#define NBKT (RB * CB)      // 20094
#define OFFSTRIDE (NBKT + 4)

typedef short short8 __attribute__((ext_vector_type(8)));
typedef float f32x4 __attribute__((ext_vector_type(4)));

// float -> bf16 (RNE) as ushort
__device__ inline unsigned bf1(float a) {
    unsigned u = __float_as_uint(a);
    return (u + 0x7FFFu + ((u >> 16) & 1u)) >> 16;
}
__device__ inline unsigned bfpack(float a, float b) {
    return bf1(a) | (bf1(b) << 16);
}

// Pose one atom -> (X, Y) in physical coords (identical code in count/scatter
// => bit-identical results).
__device__ inline float2 pose_one(const float* __restrict__ crd,
                                  const float* __restrict__ rot,
                                  const float* __restrict__ rot_init,
                                  const float* __restrict__ trans, int idx) {
    int b = idx >> 13;
    const float* p = crd + (long)idx * 3;
    float x0 = p[0], y0 = p[1], z0 = p[2];
    float q0 = x0 * rot_init[0] + y0 * rot_init[3] + z0 * rot_init[6] + trans[0];
    float q1 = x0 * rot_init[1] + y0 * rot_init[4] + z0 * rot_init[7] + trans[1];
    float q2 = x0 * rot_init[2] + y0 * rot_init[5] + z0 * rot_init[8] + trans[2];
    const float* R = rot + b * 9;
    float2 o;
    o.x = q0 * R[0] + q1 * R[1] + q2 * R[2];
    o.y = q0 * R[3] + q1 * R[4] + q2 * R[5];
    return o;
}

// ---------------------------------------------------------------------------
// Bucketing: count -> per-image flat exclusive scan -> scatter.
// ---------------------------------------------------------------------------
__global__ void count_atoms(const float* __restrict__ crd,
                            const float* __restrict__ rot,
                            const float* __restrict__ rot_init,
                            const float* __restrict__ trans,
                            int* __restrict__ counts) {
    int idx = blockIdx.x * 256 + threadIdx.x;
    float2 v = pose_one(crd, rot, rot_init, trans, idx);
    int icx = (int)rintf(v.x + 192.0f);
    int icy = (int)rintf(v.y + 192.0f);
    if (icx < -5 || icx > 388 || icy < -5 || icy > 388) return;
    int bi = (icy + 5) * CB + ((icx + 16) >> 3);
    atomicAdd(&counts[(idx >> 13) * NBKT + bi], 1);
}

__global__ __launch_bounds__(256) void bucket_scan(int* __restrict__ counts,
                                                   int* __restrict__ offs) {
    int b = blockIdx.x, t = threadIdx.x;
    const int PER = (NBKT + 255) / 256;  // 79
    int* cnt = counts + b * NBKT;
    int* off = offs + b * OFFSTRIDE;
    int base = t * PER;
    int s = 0;
    for (int i = 0; i < PER; i++) {
        int k = base + i;
        if (k < NBKT) s += cnt[k];
    }
    __shared__ int part[256];
    part[t] = s;
    __syncthreads();
    for (int d = 1; d < 256; d <<= 1) {
        int v = (t >= d) ? part[t - d] : 0;
        __syncthreads();
        part[t] += v;
        __syncthreads();
    }
    int run = (t == 0) ? 0 : part[t - 1];
    for (int i = 0; i < PER; i++) {
        int k = base + i;
        if (k < NBKT) {
            off[k] = run;
            run += cnt[k];
            cnt[k] = 0;  // reuse as scatter cursor
        }
    }
    if (base <= NBKT - 1 && NBKT - 1 < base + PER) off[NBKT] = run;  // total
}

__global__ void scatter_atoms(const float* __restrict__ crd,
                              const float* __restrict__ rot,
                              const float* __restrict__ rot_init,
                              const float* __restrict__ trans,
                              int* __restrict__ cursors,
                              const int* __restrict__ offs,
                              float2* __restrict__ sorted) {
    int idx = blockIdx.x * 256 + threadIdx.x;
    float2 v = pose_one(crd, rot, rot_init, trans, idx);
    int icx = (int)rintf(v.x + 192.0f);
    int icy = (int)rintf(v.y + 192.0f);
    if (icx < -5 || icx > 388 || icy < -5 || icy > 388) return;
    int b = idx >> 13;
    int bi = (icy + 5) * CB + ((icx + 16) >> 3);
    int pos = offs[b * OFFSTRIDE + bi] + atomicAdd(&cursors[b * NBKT + bi], 1);
    sorted[(long)b * NATOM + pos] = v;
}

// ---------------------------------------------------------------------------
// Atomic-free register-gather splat (R1/R2: LDS float atomics serialize at
// ~155 cyc/wave-op regardless of address pattern -> scatter floors ~340us).
// One WAVE owns a 16x16 px tile; lanes form an 8x8 grid, each lane keeps its
// 2x2 pixels (stride 8) in VGPRs. The wave walks 26 per-px-row bucket
// segments covering rows [r0-5, r0+20]; with 8-px col buckets the loaded
// x-window is 32px for the needed 26px (19% skip, was 46% at 16px buckets).
// ---------------------------------------------------------------------------
__global__ __launch_bounds__(256) void splat_gather(const float2* __restrict__ sorted,
                                                    const int* __restrict__ offs,
                                                    float* __restrict__ img) {
    int b = blockIdx.z;
    int wv = __builtin_amdgcn_readfirstlane((int)(threadIdx.x >> 6));
    int lane = threadIdx.x & 63;
    int tx = blockIdx.x * 4 + wv;      // 0..23
    int ty = blockIdx.y;               // 0..23
    int c0 = tx * 16, r0 = ty * 16;
    int lx = lane & 7, ly = lane >> 3; // 8x8 lane grid
    // lane owns cols {c0+lx, c0+lx+8}, rows {r0+ly, r0+ly+8}

    const int* off = offs + b * OFFSTRIDE;
    const float2* srt = sorted + (long)b * NATOM;

    int cb_lo = (c0 + 11) >> 3;          // icx >= c0-8 (covers c0-5)
    int cb_end = ((c0 + 36) >> 3) + 1;   // icx <= c0+23 (covers c0+20), excl

    float acc00 = 0.f, acc01 = 0.f, acc10 = 0.f, acc11 = 0.f;
    float pxf0 = (float)(c0 + lx - 192);
    float pyf0 = (float)(r0 + ly - 192);
    int px0 = c0 + lx, py0 = r0 + ly;
    const float kneg = -(1.0f / 4.5f) * 1.44269504088896f;  // -inv2s2*log2(e)

    for (int rb = r0; rb < r0 + 26; rb++) {  // icy = rb-5 in [r0-5, r0+20]
        int i0 = off[rb * CB + cb_lo];
        int i1 = off[rb * CB + cb_end];      // flat scan: next bucket's start
        for (int i = i0; i < i1; i++) {
            float2 v = srt[i];               // wave-uniform load
            float X = v.x, Y = v.y;
            int icx = (int)rintf(X + 192.0f);
            if ((unsigned)(icx - c0 + 5) > 25u) continue;  // uniform x-skip
            int icy = (int)rintf(Y + 192.0f);
            float fx0 = pxf0 - X, fx1 = fx0 + 8.0f;
            float fy0 = pyf0 - Y, fy1 = fy0 + 8.0f;
            int dx = px0 - icx, dy = py0 - icy;
            float ex0 = ((unsigned)(dx + 5) < 11u) ? exp2f(fx0 * fx0 * kneg) : 0.0f;
            float ex1 = ((unsigned)(dx + 13) < 11u) ? exp2f(fx1 * fx1 * kneg) : 0.0f;
            float ey0 = ((unsigned)(dy + 5) < 11u) ? exp2f(fy0 * fy0 * kneg) : 0.0f;
            float ey1 = ((unsigned)(dy + 13) < 11u) ? exp2f(fy1 * fy1 * kneg) : 0.0f;
            acc00 += ex0 * ey0;
            acc01 += ex1 * ey0;
            acc10 += ex0 * ey1;
            acc11 += ex1 * ey1;
        }
    }

    float* dst = img + ((long)b * DD + r0 + ly) * DD + c0 + lx;
    dst[0] = acc00;
    dst[8] = acc01;
    dst[8 * DD] = acc10;
    dst[8 * DD + 8] = acc11;
}

// ---------------------------------------------------------------------------
// DFT-derived weights (bf16): Bt1 = [U; S] (768x384), Bt2 = [U|-2S] (384x768).
// y = U*Y*U - 2*S*Y*S == Re(f)-Im(f) of double-fftshifted FFT2.
// ---------------------------------------------------------------------------
__global__ void gen_w(unsigned short* __restrict__ Bt1,
                      unsigned short* __restrict__ Bt2) {
    int idx = blockIdx.x * 256 + threadIdx.x;
    if (idx >= DD * DD) return;
    int i = idx / DD, j = idx % DD;
    int t = (i - 192) * (j - 192);
    int r = t % DD;
    if (r < 0) r += DD;
    float th = (float)r * (6.28318530717958647692f / (float)DD);
    float s = sinf(th), c = cosf(th);
    Bt1[i * DD + j] = (unsigned short)bf1(c + s);
    Bt1[(DD + i) * DD + j] = (unsigned short)bf1(s);
    Bt2[i * 768 + j] = (unsigned short)bf1(c + s);
    Bt2[i * 768 + 384 + j] = (unsigned short)bf1(-2.0f * s);
}

// ---------------------------------------------------------------------------
// bf16 MFMA GEMM: C[row][col] = sum_k A[row][k] * B[col][k].
// A is the SHARED bf16 weight matrix (row stride K). B is BATCHED (stride sB):
//   BF32:  B is f32, converted to bf16 (RNE) during staging (stage 1: B = Y).
//   BFOLD: B is the folded view of C' (768x384 bf16): B[i][k] =
//          k<384 ? C'[i][k] : C'[384+i][k-384]  (stage 2) -- this absorbs the
//          former fold_transpose kernel into addressing.
// Operand-swap note: putting the weights in A and the batched matrix in B
// makes C come out TRANSPOSED vs the old orientation, which (a) lets stage 1
// emit Z^T directly and (b) lets stage 2 emit y directly (no transpose
// kernels). Products and k-summation order are unchanged => bit-identical.
// ---------------------------------------------------------------------------
template <bool BF32, bool CBF16, bool BFOLD>
__global__ __launch_bounds__(256) void gemm_mfma(const unsigned short* __restrict__ Ag,
                                                 const void* __restrict__ Bg, long sB,
                                                 void* __restrict__ Cg, long sC,
                                                 int K, int ldc) {
    __shared__ uint4 lds4[2048];  // A: [0,1024), B: [1024,2048)

    int bz = blockIdx.z;
    int m0 = blockIdx.y * 128, n0 = blockIdx.x * 128;
    int tid = threadIdx.x;
    int lane = tid & 63, w = tid >> 6;
    int wm = w >> 1, wn = w & 1;

    f32x4 acc[4][4];
#pragma unroll
    for (int i = 0; i < 4; i++)
#pragma unroll
        for (int j = 0; j < 4; j++) acc[i][j] = (f32x4){0.f, 0.f, 0.f, 0.f};

    const float* Bf = (const float*)Bg + (long)bz * sB;
    const unsigned short* Bh = (const unsigned short*)Bg + (long)bz * sB;

    for (int k0 = 0; k0 < K; k0 += 64) {
        __syncthreads();
#pragma unroll
        for (int cc = 0; cc < 4; cc++) {
            int c = tid + cc * 256;
            int m = c >> 3, kc = (c & 7) << 3;
            int li = ((m >> 4) * 2 + (kc >> 5)) * 64 +
                     ((m & 15) | (((kc >> 3) & 3) << 4));
            // A tile (shared weights, always bf16, row stride K)
            lds4[li] = *(const uint4*)(Ag + (long)(m0 + m) * K + k0 + kc);
            // B tile (batched)
            uint4 wv;
            if (BF32) {
                const float* p = Bf + (long)(n0 + m) * K + k0 + kc;
                float4 lo = *(const float4*)p;
                float4 hi = *(const float4*)(p + 4);
                wv.x = bfpack(lo.x, lo.y); wv.y = bfpack(lo.z, lo.w);
                wv.z = bfpack(hi.x, hi.y); wv.w = bfpack(hi.z, hi.w);
            } else if (BFOLD) {
                int kk = k0 + kc;  // 16B run stays within one 384-half (64|384)
                long boff = (kk >= 384)
                                ? ((long)(384 + n0 + m) * 384 + (kk - 384))
                                : ((long)(n0 + m) * 384 + kk);
                wv = *(const uint4*)(Bh + boff);
            } else {
                wv = *(const uint4*)(Bh + (long)(n0 + m) * K + k0 + kc);
            }
            lds4[1024 + li] = wv;
        }
        __syncthreads();
#pragma unroll
        for (int ki = 0; ki < 2; ki++) {
            short8 a[4], bfr[4];
#pragma unroll
            for (int i = 0; i < 4; i++)
                a[i] = *(const short8*)&lds4[((wm * 4 + i) * 2 + ki) * 64 + lane];
#pragma unroll
            for (int j = 0; j < 4; j++)
                bfr[j] = *(const short8*)&lds4[1024 + ((wn * 4 + j) * 2 + ki) * 64 + lane];
#pragma unroll
            for (int i = 0; i < 4; i++)
#pragma unroll
                for (int j = 0; j < 4; j++)
                    acc[i][j] = __builtin_amdgcn_mfma_f32_16x16x32_bf16(
                        a[i], bfr[j], acc[i][j], 0, 0, 0);
        }
    }

    int quad = lane >> 4, col0 = lane & 15;
#pragma unroll
    for (int i = 0; i < 4; i++)
#pragma unroll
        for (int j = 0; j < 4; j++)
#pragma unroll
            for (int r = 0; r < 4; r++) {
                int row = m0 + (wm * 4 + i) * 16 + quad * 4 + r;
                int cc2 = n0 + (wn * 4 + j) * 16 + col0;
                if (CBF16)
                    ((unsigned short*)Cg + (long)bz * sC)[(long)row * ldc + cc2] =
                        (unsigned short)bf1(acc[i][j][r]);
                else
                    ((float*)Cg + (long)bz * sC)[(long)row * ldc + cc2] = acc[i][j][r];
            }
}

extern "C" void kernel_launch(void* const* d_in, const int* in_sizes, int n_in,
                              void* d_out, int out_size, void* d_ws, size_t ws_size,
                              hipStream_t stream) {
    const float* crd      = (const float*)d_in[0];
    const float* rot      = (const float*)d_in[1];
    const float* rot_init = (const float*)d_in[2];
    const float* trans    = (const float*)d_in[3];

    float* out   = (float*)d_out;
    float* y     = out;                          // [64,384,384] hartley (fp32)
    float* yreal = out + (size_t)NB * DD * DD;   // [64,384,384] real image

    char* ws = (char*)d_ws;
    unsigned short* Bt1 = (unsigned short*)ws;              // [U;S]   768x384
    unsigned short* Bt2 = (unsigned short*)(ws + 589824);   // [U|-2S] 384x768
    char* Zb = ws + 1179648;                                // Z region (37.7MB)
    unsigned short* Z = (unsigned short*)Zb;                // 64x768x384 bf16 (Z^T)
    // Bucketing scratch aliases Z (all dead before stage-1 GEMM writes Z):
    int*    counts = (int*)Zb;                              // 64*20094*4 = 5,144,064 B
    int*    offs   = (int*)(Zb + 5144064);                  // 64*20098*4 = 5,145,088 B
    float2* sorted = (float2*)(Zb + 10289152);              // 4,194,304 B

    hipMemsetAsync(counts, 0, (size_t)NB * NBKT * 4, stream);

    count_atoms<<<(NB * NATOM) / 256, 256, 0, stream>>>(crd, rot, rot_init, trans, counts);
    bucket_scan<<<NB, 256, 0, stream>>>(counts, offs);
    scatter_atoms<<<(NB * NATOM) / 256, 256, 0, stream>>>(crd, rot, rot_init, trans,
                                                          counts, offs, sorted);
    splat_gather<<<dim3(6, 24, NB), 256, 0, stream>>>(sorted, offs, yreal);

    gen_w<<<(DD * DD + 255) / 256, 256, 0, stream>>>(Bt1, Bt2);

    // Stage 1 (swapped): C'[v][k] = sum_m Bt1[v][m]*Y[k][m] = Z^T,
    // M=768, N=384, K=384; A=Bt1 shared, B=Y batched f32->bf16, C bf16.
    gemm_mfma<true, true, false><<<dim3(3, 6, NB), 256, 0, stream>>>(
        Bt1, (const void*)yreal, (long)DD * DD, (void*)Z, (long)768 * DD, DD, DD);

    // Stage 2 (swapped, folded-B): y[j][i] = sum_k Bt2[j][k]*Zt[i][k],
    // M=N=384, K=768; A=Bt2 shared, B=C' via fold addressing, C=y f32 direct.
    gemm_mfma<false, false, true><<<dim3(3, 3, NB), 256, 0, stream>>>(
        Bt2, (const void*)Z, (long)768 * DD, (void*)y, (long)DD * DD, 768, DD);
}

// Round 6
// 344.924 us; speedup vs baseline: 2.4049x; 1.4284x over previous
//
#include <hip/hip_runtime.h>

#define DD 384
#define NB 64
#define NATOM 8192
#define RB 394              // row buckets: icy+5, icy in [-5,388]
#define CB 51               // col buckets: (icx+16)>>3, icx in [-5,388] -> [1,50]
#define NBKT (RB * CB)      // 20094
#define OFFSTRIDE (NBKT + 4)

typedef short short8 __attribute__((ext_vector_type(8)));
typedef float f32x4 __attribute__((ext_vector_type(4)));
typedef unsigned u32x4 __attribute__((ext_vector_type(4)));

// float -> bf16 (RNE) as ushort
__device__ inline unsigned bf1(float a) {
    unsigned u = __float_as_uint(a);
    return (u + 0x7FFFu + ((u >> 16) & 1u)) >> 16;
}
__device__ inline unsigned bfpack(float a, float b) {
    return bf1(a) | (bf1(b) << 16);
}

// Pose one atom -> (X, Y) in physical coords (identical code in count/scatter
// => bit-identical results).
__device__ inline float2 pose_one(const float* __restrict__ crd,
                                  const float* __restrict__ rot,
                                  const float* __restrict__ rot_init,
                                  const float* __restrict__ trans, int idx) {
    int b = idx >> 13;
    const float* p = crd + (long)idx * 3;
    float x0 = p[0], y0 = p[1], z0 = p[2];
    float q0 = x0 * rot_init[0] + y0 * rot_init[3] + z0 * rot_init[6] + trans[0];
    float q1 = x0 * rot_init[1] + y0 * rot_init[4] + z0 * rot_init[7] + trans[1];
    float q2 = x0 * rot_init[2] + y0 * rot_init[5] + z0 * rot_init[8] + trans[2];
    const float* R = rot + b * 9;
    float2 o;
    o.x = q0 * R[0] + q1 * R[1] + q2 * R[2];
    o.y = q0 * R[3] + q1 * R[4] + q2 * R[5];
    return o;
}

// ---------------------------------------------------------------------------
// Bucketing: count -> per-image flat exclusive scan -> scatter.
// ---------------------------------------------------------------------------
__global__ void count_atoms(const float* __restrict__ crd,
                            const float* __restrict__ rot,
                            const float* __restrict__ rot_init,
                            const float* __restrict__ trans,
                            int* __restrict__ counts) {
    int idx = blockIdx.x * 256 + threadIdx.x;
    float2 v = pose_one(crd, rot, rot_init, trans, idx);
    int icx = (int)rintf(v.x + 192.0f);
    int icy = (int)rintf(v.y + 192.0f);
    if (icx < -5 || icx > 388 || icy < -5 || icy > 388) return;
    int bi = (icy + 5) * CB + ((icx + 16) >> 3);
    atomicAdd(&counts[(idx >> 13) * NBKT + bi], 1);
}

__global__ __launch_bounds__(256) void bucket_scan(int* __restrict__ counts,
                                                   int* __restrict__ offs) {
    int b = blockIdx.x, t = threadIdx.x;
    const int PER = (NBKT + 255) / 256;  // 79
    int* cnt = counts + b * NBKT;
    int* off = offs + b * OFFSTRIDE;
    int base = t * PER;
    int s = 0;
    for (int i = 0; i < PER; i++) {
        int k = base + i;
        if (k < NBKT) s += cnt[k];
    }
    __shared__ int part[256];
    part[t] = s;
    __syncthreads();
    for (int d = 1; d < 256; d <<= 1) {
        int v = (t >= d) ? part[t - d] : 0;
        __syncthreads();
        part[t] += v;
        __syncthreads();
    }
    int run = (t == 0) ? 0 : part[t - 1];
    for (int i = 0; i < PER; i++) {
        int k = base + i;
        if (k < NBKT) {
            off[k] = run;
            run += cnt[k];
            cnt[k] = 0;  // reuse as scatter cursor
        }
    }
    if (base <= NBKT - 1 && NBKT - 1 < base + PER) off[NBKT] = run;  // total
}

__global__ void scatter_atoms(const float* __restrict__ crd,
                              const float* __restrict__ rot,
                              const float* __restrict__ rot_init,
                              const float* __restrict__ trans,
                              int* __restrict__ cursors,
                              const int* __restrict__ offs,
                              float2* __restrict__ sorted) {
    int idx = blockIdx.x * 256 + threadIdx.x;
    float2 v = pose_one(crd, rot, rot_init, trans, idx);
    int icx = (int)rintf(v.x + 192.0f);
    int icy = (int)rintf(v.y + 192.0f);
    if (icx < -5 || icx > 388 || icy < -5 || icy > 388) return;
    int b = idx >> 13;
    int bi = (icy + 5) * CB + ((icx + 16) >> 3);
    int pos = offs[b * OFFSTRIDE + bi] + atomicAdd(&cursors[b * NBKT + bi], 1);
    sorted[(long)b * NATOM + pos] = v;
}

// ---------------------------------------------------------------------------
// MFMA splat. The gaussian is separable: per atom the tile contribution is
// the outer product ey (x) ex, so per 16x16 tile IMG = sum_a ey_a (x) ex_a =
// E_y^T * E_x  -- a GEMM with K = atoms. mfma_f32_16x16x32_bf16 does 32
// atoms per instruction. One wave per tile:
//   Phase 1: lanes 0..25 (one per row-bucket) copy the tile's atom window
//            (contiguous bucket segments) into a per-wave LDS list; shfl
//            prefix-scan gives placement; pad to x32 with sentinel atoms
//            (X=Y=3e5 -> masked to 0). Bounded streaming rounds (<=24; worst
//            case 8192/512=16) handle overflow -- hang-proof by construction.
//   Phase 2: per 32-atom chunk each lane computes ey for row lane&15 /
//            ex for col lane&15 of its 8 atoms (k-slice (lane>>4)*8, same
//            fragment layout as gemm_mfma below), hard |d|<=5 mask identical
//            to the reference, bf16 RNE pack via bfpack (proven path), 1 MFMA.
// Every (atom,pixel) pair computed exactly once; no atomics (R1/R2: LDS
// float atomics serialize ~155cyc/wave-op -> scatter floors ~340us), and no
// lane-redundant scalar math (R3/R4 gather: ~106 VALU instr/visit).
// Wave-private LDS producer/consumer: s_waitcnt lgkmcnt(0) (NOT __syncthreads
// -- waves run different round counts, a block barrier would deadlock) +
// sched_barrier to stop any consumer being hoisted above the wait.
// ---------------------------------------------------------------------------
#define LCAP 512
#define LSZ  544   // LCAP + 32 pad slots

__global__ __launch_bounds__(256) void splat_mfma(const float2* __restrict__ sorted,
                                                  const int* __restrict__ offs,
                                                  float* __restrict__ img) {
    __shared__ __align__(16) float2 list[4][LSZ];
    int b = blockIdx.z;
    int wv = __builtin_amdgcn_readfirstlane((int)(threadIdx.x >> 6));
    int lane = threadIdx.x & 63;
    int tx = blockIdx.x * 4 + wv;      // 0..23
    int ty = blockIdx.y;               // 0..23
    int c0 = tx * 16, r0 = ty * 16;

    const int* off = offs + b * OFFSTRIDE;
    const float2* srt = sorted + (long)b * NATOM;

    int cb_lo = (c0 + 11) >> 3;          // loaded x-window [c0-8, c0+23]
    int cb_end = ((c0 + 36) >> 3) + 1;

    int cur = 0, iend = 0;
    if (lane < 26) {                     // one lane per row-bucket
        int rb = r0 + lane;              // icy = rb-5 in [r0-5, r0+20]
        cur = off[rb * CB + cb_lo];
        iend = off[rb * CB + cb_end];
    }

    f32x4 acc = {0.f, 0.f, 0.f, 0.f};
    int m = lane & 15;
    float rowf = (float)(r0 + m);        // a-side: pixel row (0..383)
    float colf = (float)(c0 + m);        // b-side: pixel col
    float py = rowf - 192.0f, px = colf - 192.0f;
    int g8 = (lane >> 4) << 3;           // k-slice base within chunk
    const float kneg = -0.32059868f;     // -(1/4.5)*log2(e)
    float2* wl = list[wv];

    for (int round = 0; round < 24; ++round) {
        int len = (lane < 26) ? (iend - cur) : 0;
        int incl = len;                  // exclusive scan via shfl_up
#pragma unroll
        for (int d = 1; d < 64; d <<= 1) {
            int t = __shfl_up(incl, d);
            if (lane >= d) incl += t;
        }
        int excl = incl - len;
        int totrem = __builtin_amdgcn_readfirstlane(__shfl(incl, 63));
        if (totrem == 0) break;
        int total = min(totrem, LCAP);
        int cnt = min(len, max(0, LCAP - excl));
        for (int j = 0; j < cnt; j++) wl[excl + j] = srt[cur + j];
        cur += cnt;
        int padn = (32 - (total & 31)) & 31;
        if (lane < padn) wl[total + lane] = (float2){3.0e5f, 3.0e5f};
        asm volatile("s_waitcnt lgkmcnt(0)" ::: "memory");  // wave-local LDS fence
        __builtin_amdgcn_sched_barrier(0);                  // no hoist past fence

        int nch = (total + 31) >> 5;
        for (int ch = 0; ch < nch; ch++) {
            const f32x4* qp = (const f32x4*)&wl[ch * 32 + g8];  // 2 atoms per read
            u32x4 au, bu;
#pragma unroll
            for (int p = 0; p < 4; p++) {
                f32x4 q = qp[p];         // (X0,Y0,X1,Y1); 16-lane broadcast
                // ey (row side)
                float d0 = py - q[1], d1 = py - q[3];
                float cy0 = rintf(q[1] + 192.0f), cy1 = rintf(q[3] + 192.0f);
                float e0 = (fabsf(rowf - cy0) <= 5.0f) ? exp2f(d0 * d0 * kneg) : 0.0f;
                float e1 = (fabsf(rowf - cy1) <= 5.0f) ? exp2f(d1 * d1 * kneg) : 0.0f;
                au[p] = bfpack(e0, e1);
                // ex (col side)
                float f0 = px - q[0], f1 = px - q[2];
                float cx0 = rintf(q[0] + 192.0f), cx1 = rintf(q[2] + 192.0f);
                float g0 = (fabsf(colf - cx0) <= 5.0f) ? exp2f(f0 * f0 * kneg) : 0.0f;
                float g1 = (fabsf(colf - cx1) <= 5.0f) ? exp2f(f1 * f1 * kneg) : 0.0f;
                bu[p] = bfpack(g0, g1);
            }
            short8 af = __builtin_bit_cast(short8, au);
            short8 bf = __builtin_bit_cast(short8, bu);
            acc = __builtin_amdgcn_mfma_f32_16x16x32_bf16(af, bf, acc, 0, 0, 0);
        }
        if (totrem <= LCAP) break;       // everything consumed this round
    }

    // C layout: col = lane&15, row = (lane>>4)*4 + r  (same as gemm_mfma)
    int col = c0 + m;
    int rbase = r0 + (lane >> 4) * 4;
#pragma unroll
    for (int r = 0; r < 4; r++)
        img[((long)b * DD + rbase + r) * DD + col] = acc[r];
}

// ---------------------------------------------------------------------------
// DFT-derived weights (bf16): Bt1 = [U; S] (768x384), Bt2 = [U|-2S] (384x768).
// y = U*Y*U - 2*S*Y*S == Re(f)-Im(f) of double-fftshifted FFT2.
// ---------------------------------------------------------------------------
__global__ void gen_w(unsigned short* __restrict__ Bt1,
                      unsigned short* __restrict__ Bt2) {
    int idx = blockIdx.x * 256 + threadIdx.x;
    if (idx >= DD * DD) return;
    int i = idx / DD, j = idx % DD;
    int t = (i - 192) * (j - 192);
    int r = t % DD;
    if (r < 0) r += DD;
    float th = (float)r * (6.28318530717958647692f / (float)DD);
    float s = sinf(th), c = cosf(th);
    Bt1[i * DD + j] = (unsigned short)bf1(c + s);
    Bt1[(DD + i) * DD + j] = (unsigned short)bf1(s);
    Bt2[i * 768 + j] = (unsigned short)bf1(c + s);
    Bt2[i * 768 + 384 + j] = (unsigned short)bf1(-2.0f * s);
}

// ---------------------------------------------------------------------------
// bf16 MFMA GEMM: C[row][col] = sum_k A[row][k] * B[col][k].
// A is the SHARED bf16 weight matrix (row stride K). B is BATCHED (stride sB):
//   BF32:  B is f32, converted to bf16 (RNE) during staging (stage 1: B = Y).
//   BFOLD: B is the folded view of C' (768x384 bf16): B[i][k] =
//          k<384 ? C'[i][k] : C'[384+i][k-384]  (stage 2) -- this absorbs the
//          former fold_transpose kernel into addressing.
// Operand-swap note: putting the weights in A and the batched matrix in B
// makes C come out TRANSPOSED vs the old orientation, which (a) lets stage 1
// emit Z^T directly and (b) lets stage 2 emit y directly (no transpose
// kernels). Products and k-summation order are unchanged => bit-identical.
// ---------------------------------------------------------------------------
template <bool BF32, bool CBF16, bool BFOLD>
__global__ __launch_bounds__(256) void gemm_mfma(const unsigned short* __restrict__ Ag,
                                                 const void* __restrict__ Bg, long sB,
                                                 void* __restrict__ Cg, long sC,
                                                 int K, int ldc) {
    __shared__ uint4 lds4[2048];  // A: [0,1024), B: [1024,2048)

    int bz = blockIdx.z;
    int m0 = blockIdx.y * 128, n0 = blockIdx.x * 128;
    int tid = threadIdx.x;
    int lane = tid & 63, w = tid >> 6;
    int wm = w >> 1, wn = w & 1;

    f32x4 acc[4][4];
#pragma unroll
    for (int i = 0; i < 4; i++)
#pragma unroll
        for (int j = 0; j < 4; j++) acc[i][j] = (f32x4){0.f, 0.f, 0.f, 0.f};

    const float* Bf = (const float*)Bg + (long)bz * sB;
    const unsigned short* Bh = (const unsigned short*)Bg + (long)bz * sB;

    for (int k0 = 0; k0 < K; k0 += 64) {
        __syncthreads();
#pragma unroll
        for (int cc = 0; cc < 4; cc++) {
            int c = tid + cc * 256;
            int m = c >> 3, kc = (c & 7) << 3;
            int li = ((m >> 4) * 2 + (kc >> 5)) * 64 +
                     ((m & 15) | (((kc >> 3) & 3) << 4));
            // A tile (shared weights, always bf16, row stride K)
            lds4[li] = *(const uint4*)(Ag + (long)(m0 + m) * K + k0 + kc);
            // B tile (batched)
            uint4 wv;
            if (BF32) {
                const float* p = Bf + (long)(n0 + m) * K + k0 + kc;
                float4 lo = *(const float4*)p;
                float4 hi = *(const float4*)(p + 4);
                wv.x = bfpack(lo.x, lo.y); wv.y = bfpack(lo.z, lo.w);
                wv.z = bfpack(hi.x, hi.y); wv.w = bfpack(hi.z, hi.w);
            } else if (BFOLD) {
                int kk = k0 + kc;  // 16B run stays within one 384-half (64|384)
                long boff = (kk >= 384)
                                ? ((long)(384 + n0 + m) * 384 + (kk - 384))
                                : ((long)(n0 + m) * 384 + kk);
                wv = *(const uint4*)(Bh + boff);
            } else {
                wv = *(const uint4*)(Bh + (long)(n0 + m) * K + k0 + kc);
            }
            lds4[1024 + li] = wv;
        }
        __syncthreads();
#pragma unroll
        for (int ki = 0; ki < 2; ki++) {
            short8 a[4], bfr[4];
#pragma unroll
            for (int i = 0; i < 4; i++)
                a[i] = *(const short8*)&lds4[((wm * 4 + i) * 2 + ki) * 64 + lane];
#pragma unroll
            for (int j = 0; j < 4; j++)
                bfr[j] = *(const short8*)&lds4[1024 + ((wn * 4 + j) * 2 + ki) * 64 + lane];
#pragma unroll
            for (int i = 0; i < 4; i++)
#pragma unroll
                for (int j = 0; j < 4; j++)
                    acc[i][j] = __builtin_amdgcn_mfma_f32_16x16x32_bf16(
                        a[i], bfr[j], acc[i][j], 0, 0, 0);
        }
    }

    int quad = lane >> 4, col0 = lane & 15;
#pragma unroll
    for (int i = 0; i < 4; i++)
#pragma unroll
        for (int j = 0; j < 4; j++)
#pragma unroll
            for (int r = 0; r < 4; r++) {
                int row = m0 + (wm * 4 + i) * 16 + quad * 4 + r;
                int cc2 = n0 + (wn * 4 + j) * 16 + col0;
                if (CBF16)
                    ((unsigned short*)Cg + (long)bz * sC)[(long)row * ldc + cc2] =
                        (unsigned short)bf1(acc[i][j][r]);
                else
                    ((float*)Cg + (long)bz * sC)[(long)row * ldc + cc2] = acc[i][j][r];
            }
}

extern "C" void kernel_launch(void* const* d_in, const int* in_sizes, int n_in,
                              void* d_out, int out_size, void* d_ws, size_t ws_size,
                              hipStream_t stream) {
    const float* crd      = (const float*)d_in[0];
    const float* rot      = (const float*)d_in[1];
    const float* rot_init = (const float*)d_in[2];
    const float* trans    = (const float*)d_in[3];

    float* out   = (float*)d_out;
    float* y     = out;                          // [64,384,384] hartley (fp32)
    float* yreal = out + (size_t)NB * DD * DD;   // [64,384,384] real image

    char* ws = (char*)d_ws;
    unsigned short* Bt1 = (unsigned short*)ws;              // [U;S]   768x384
    unsigned short* Bt2 = (unsigned short*)(ws + 589824);   // [U|-2S] 384x768
    char* Zb = ws + 1179648;                                // Z region (37.7MB)
    unsigned short* Z = (unsigned short*)Zb;                // 64x768x384 bf16 (Z^T)
    // Bucketing scratch aliases Z (all dead before stage-1 GEMM writes Z):
    int*    counts = (int*)Zb;                              // 64*20094*4 = 5,144,064 B
    int*    offs   = (int*)(Zb + 5144064);                  // 64*20098*4 = 5,145,088 B
    float2* sorted = (float2*)(Zb + 10289152);              // 4,194,304 B

    hipMemsetAsync(counts, 0, (size_t)NB * NBKT * 4, stream);

    count_atoms<<<(NB * NATOM) / 256, 256, 0, stream>>>(crd, rot, rot_init, trans, counts);
    bucket_scan<<<NB, 256, 0, stream>>>(counts, offs);
    scatter_atoms<<<(NB * NATOM) / 256, 256, 0, stream>>>(crd, rot, rot_init, trans,
                                                          counts, offs, sorted);
    splat_mfma<<<dim3(6, 24, NB), 256, 0, stream>>>(sorted, offs, yreal);

    gen_w<<<(DD * DD + 255) / 256, 256, 0, stream>>>(Bt1, Bt2);

    // Stage 1 (swapped): C'[v][k] = sum_m Bt1[v][m]*Y[k][m] = Z^T,
    // M=768, N=384, K=384; A=Bt1 shared, B=Y batched f32->bf16, C bf16.
    gemm_mfma<true, true, false><<<dim3(3, 6, NB), 256, 0, stream>>>(
        Bt1, (const void*)yreal, (long)DD * DD, (void*)Z, (long)768 * DD, DD, DD);

    // Stage 2 (swapped, folded-B): y[j][i] = sum_k Bt2[j][k]*Zt[i][k],
    // M=N=384, K=768; A=Bt2 shared, B=C' via fold addressing, C=y f32 direct.
    gemm_mfma<false, false, true><<<dim3(3, 3, NB), 256, 0, stream>>>(
        Bt2, (const void*)Z, (long)768 * DD, (void*)y, (long)DD * DD, 768, DD);
}